// Round 4
// baseline (18.682 us; speedup 1.0000x reference)
//
#include <hip/hip_runtime.h>
#include <math.h>

// Epps-Pulley statistic, B=16 rows of N=4096 fp32 — ONE kernel, one block/row.
// Per row everything reduces to 48 weighted moments:
//   S_n = sum_i w_i xs_i^n,  w_i = exp(-xs_i^2/2)
//   term1 = (1/N^2) sum_n S_n^2 / n!              (Mercer expansion)
//   term2 = (-2/NK) sum_k w_gk sum_n S_n g_k^n / n!
//   term3 = (1/K^2) sum_kl exp(-(g_k-g_l)^2/2)
// 16 blocks x 1024 threads (4 elems/thread). Stats in f64, moments in f32
// chains, wave reduction on the VALU pipe via DPP, 16-wave LDS combine,
// finish in-block in f64. No workspace, no atomics, fully deterministic.

#define N_ELEM 4096
#define BATCH  16
#define NPTS   17
#define NM     48                 // moments n = 0..47; series tail < 1e-12
#define NWAVE  16                 // 1024 threads
#define L2E  1.4426950408889634f
#define HL2E 0.7213475204444817f  // 0.5*log2(e)

#if defined(__has_builtin)
#if __has_builtin(__builtin_amdgcn_exp2f)
#define EXP2(x) __builtin_amdgcn_exp2f(x)
#else
#define EXP2(x) exp2f(x)
#endif
#else
#define EXP2(x) exp2f(x)
#endif

// DPP-based wave64 reduction: 6 VALU adds, total lands in lane 63.
template<int CTRL, int RMASK>
__device__ __forceinline__ float dpp_add(float v) {
    int t = __builtin_amdgcn_update_dpp(0, __float_as_int(v), CTRL, RMASK, 0xf, false);
    return v + __int_as_float(t);
}
__device__ __forceinline__ float wave_sum63(float v) {
    v = dpp_add<0x111, 0xf>(v);   // row_shr:1
    v = dpp_add<0x112, 0xf>(v);   // row_shr:2
    v = dpp_add<0x114, 0xf>(v);   // row_shr:4
    v = dpp_add<0x118, 0xf>(v);   // row_shr:8  -> lane15 of each row16
    v = dpp_add<0x142, 0xa>(v);   // row_bcast:15 into rows 1,3
    v = dpp_add<0x143, 0xc>(v);   // row_bcast:31 into rows 2,3 -> lane63 total
    return v;
}

// Giles' single-precision erfinv — matches XLA's f32 erfinv path.
__device__ __forceinline__ float erfinv_f(float y) {
    float w = -logf((1.0f - y) * (1.0f + y));
    float p;
    if (w < 5.0f) {
        w = w - 2.5f;
        p = 2.81022636e-08f;
        p = fmaf(p, w, 3.43273939e-07f);
        p = fmaf(p, w, -3.5233877e-06f);
        p = fmaf(p, w, -4.39150654e-06f);
        p = fmaf(p, w, 0.00021858087f);
        p = fmaf(p, w, -0.00125372503f);
        p = fmaf(p, w, -0.00417768164f);
        p = fmaf(p, w, 0.246640727f);
        p = fmaf(p, w, 1.50140941f);
    } else {
        w = sqrtf(w) - 3.0f;
        p = -0.000200214257f;
        p = fmaf(p, w, 0.000100950558f);
        p = fmaf(p, w, 0.00134934322f);
        p = fmaf(p, w, -0.00367342844f);
        p = fmaf(p, w, 0.00573950773f);
        p = fmaf(p, w, -0.0076224613f);
        p = fmaf(p, w, 0.00943887047f);
        p = fmaf(p, w, 1.00167406f);
        p = fmaf(p, w, 2.83297682f);
    }
    return p * y;
}

__global__ __launch_bounds__(1024) void ep_one(const float* __restrict__ x,
                                               float* __restrict__ out) {
    __shared__ double sred[NWAVE][2];
    __shared__ double stats[2];
    __shared__ float mom[NWAVE][NM];
    __shared__ double SnL[NM], invfL[NM], cL[NM];
    __shared__ double t2L[NPTS], t3L[NPTS];
    __shared__ float gL[NPTS];

    const int b = blockIdx.x, tid = threadIdx.x;
    const int lane = tid & 63, wv = tid >> 6;
    const float4 v = ((const float4*)(x + b * N_ELEM))[tid];   // 4 elems/thread

    // reference points (wave 0, no deps)
    if (tid < NPTS) {
        float q = 0.01f + 0.06125f * (float)tid;   // linspace(0.01,0.99,17)
        gL[tid] = erfinv_f(2.0f * q - 1.0f) * 1.41421356237309515f;
    }

    // ---- row stats (f64) ----
    {
        double d0 = v.x, d1 = v.y, d2 = v.z, d3 = v.w;
        double s  = (d0 + d1) + (d2 + d3);
        double s2 = (d0 * d0 + d1 * d1) + (d2 * d2 + d3 * d3);
#pragma unroll
        for (int off = 32; off > 0; off >>= 1) {
            s  += __shfl_down(s, off, 64);
            s2 += __shfl_down(s2, off, 64);
        }
        if (lane == 0) { sred[wv][0] = s; sred[wv][1] = s2; }
    }
    __syncthreads();
    if (tid == 0) {
        double Sa = 0.0, Sb = 0.0;
#pragma unroll
        for (int w = 0; w < NWAVE; ++w) { Sa += sred[w][0]; Sb += sred[w][1]; }
        double mean = Sa / (double)N_ELEM;
        double var  = (Sb - (double)N_ELEM * mean * mean) / (double)(N_ELEM - 1);
        stats[0] = mean;
        stats[1] = 1.0 / (sqrt(var) + 1e-6);   // torch std(ddof=1) + EPS
    }
    __syncthreads();
    const double mean = stats[0], istd = stats[1];

    // ---- normalize + weights (f32) ----
    float x0 = (float)(((double)v.x - mean) * istd);
    float x1 = (float)(((double)v.y - mean) * istd);
    float x2 = (float)(((double)v.z - mean) * istd);
    float x3 = (float)(((double)v.w - mean) * istd);
    float p0 = EXP2(-HL2E * x0 * x0);
    float p1 = EXP2(-HL2E * x1 * x1);
    float p2 = EXP2(-HL2E * x2 * x2);
    float p3 = EXP2(-HL2E * x3 * x3);

    // ---- 48 moment chains, wave-reduced on the VALU pipe ----
    float S[NM];
#pragma unroll
    for (int n = 0; n < NM; ++n) {
        S[n] = (p0 + p1) + (p2 + p3);
        p0 *= x0; p1 *= x1; p2 *= x2; p3 *= x3;
    }
#pragma unroll
    for (int n = 0; n < NM; ++n) S[n] = wave_sum63(S[n]);
    if (lane == 63) {
        float4* dst = (float4*)mom[wv];
#pragma unroll
        for (int q = 0; q < NM / 4; ++q)
            dst[q] = make_float4(S[4*q], S[4*q+1], S[4*q+2], S[4*q+3]);
    }
    __syncthreads();

    // ---- combine waves + factorials (threads 0..47, wave 0) ----
    if (tid < NM) {
        double acc = 0.0;
#pragma unroll
        for (int w = 0; w < NWAVE; ++w) acc += (double)mom[w][tid];
        double f = 1.0;
        for (int i = 2; i <= tid; ++i) f *= (double)i;   // n!
        SnL[tid] = acc;
        invfL[tid] = 1.0 / f;
        cL[tid] = acc * acc / f;
    }
    __syncthreads();

    // ---- term2 / term3 (threads 0..16) ----
    if (tid < NPTS) {
        double g = (double)gL[tid];
        double pw = 1.0, acc = 0.0;
#pragma unroll
        for (int n = 0; n < NM; ++n) { acc += SnL[n] * invfL[n] * pw; pw *= g; }
        t2L[tid] = exp(-0.5 * g * g) * acc;
        double a3 = 0.0;
        for (int l = 0; l < NPTS; ++l) {
            double d = g - (double)gL[l];
            a3 += exp(-0.5 * d * d);
        }
        t3L[tid] = a3;
    }
    __syncthreads();
    if (tid == 0) {
        double t1 = 0.0;
        for (int n = 0; n < NM; ++n) t1 += cL[n];
        t1 /= (double)N_ELEM * (double)N_ELEM;
        double s2 = 0.0, s3 = 0.0;
        for (int k = 0; k < NPTS; ++k) { s2 += t2L[k]; s3 += t3L[k]; }
        out[b] = (float)(t1 - 2.0 * s2 / ((double)N_ELEM * (double)NPTS)
                            + s3 / (double)(NPTS * NPTS));
    }
}

extern "C" void kernel_launch(void* const* d_in, const int* in_sizes, int n_in,
                              void* d_out, int out_size, void* d_ws, size_t ws_size,
                              hipStream_t stream) {
    const float* x = (const float*)d_in[0];
    float* out = (float*)d_out;
    hipLaunchKernelGGL(ep_one, dim3(BATCH), dim3(1024), 0, stream, x, out);
}

// Round 5
// 14.970 us; speedup vs baseline: 1.2480x; 1.2480x over previous
//
#include <hip/hip_runtime.h>
#include <math.h>

// Epps-Pulley statistic, B=16 rows of N=4096 fp32 — ONE kernel, one block/row.
// Per row everything reduces to 48 weighted moments (Mercer expansion):
//   S_n = sum_i w_i xs_i^n,  w_i = exp(-xs_i^2/2)
//   term1 = (1/N^2) sum_n S_n^2 / n!
//   term2 = (-2/NK) sum_k w_gk sum_n S_n g_k^n / n!
//   term3 = (1/K^2) sum_kl exp(-(g_k-g_l)^2/2)
// 16 blocks x 512 threads (8 elems/thread): VGPR cap 256 (no regalloc squeeze),
// stats f64, f32 moment chains, DPP wave reduce (VALU pipe), 8-wave LDS
// combine, finish with HARDWARE f32 exp2 only (no libm f64 exp tail).

#define N_ELEM 4096
#define BATCH  16
#define NPTS   17
#define NM     48                 // moments n = 0..47; series tail < 1e-11
#define NW     8                  // waves per block (512 threads)
#define L2E  1.4426950408889634f
#define HL2E 0.7213475204444817f  // 0.5*log2(e)

#if defined(__has_builtin)
#if __has_builtin(__builtin_amdgcn_exp2f)
#define EXP2(x) __builtin_amdgcn_exp2f(x)
#else
#define EXP2(x) exp2f(x)
#endif
#else
#define EXP2(x) exp2f(x)
#endif

// DPP-based wave64 reduction: 6 VALU adds, total lands in lane 63.
template<int CTRL, int RMASK>
__device__ __forceinline__ float dpp_add(float v) {
    int t = __builtin_amdgcn_update_dpp(0, __float_as_int(v), CTRL, RMASK, 0xf, false);
    return v + __int_as_float(t);
}
__device__ __forceinline__ float wave_sum63(float v) {
    v = dpp_add<0x111, 0xf>(v);   // row_shr:1
    v = dpp_add<0x112, 0xf>(v);   // row_shr:2
    v = dpp_add<0x114, 0xf>(v);   // row_shr:4
    v = dpp_add<0x118, 0xf>(v);   // row_shr:8  -> lane15 of each row16
    v = dpp_add<0x142, 0xa>(v);   // row_bcast:15 into rows 1,3
    v = dpp_add<0x143, 0xc>(v);   // row_bcast:31 into rows 2,3 -> lane63 total
    return v;
}

// Giles' single-precision erfinv — matches XLA's f32 erfinv path.
__device__ __forceinline__ float erfinv_f(float y) {
    float w = -logf((1.0f - y) * (1.0f + y));
    float p;
    if (w < 5.0f) {
        w = w - 2.5f;
        p = 2.81022636e-08f;
        p = fmaf(p, w, 3.43273939e-07f);
        p = fmaf(p, w, -3.5233877e-06f);
        p = fmaf(p, w, -4.39150654e-06f);
        p = fmaf(p, w, 0.00021858087f);
        p = fmaf(p, w, -0.00125372503f);
        p = fmaf(p, w, -0.00417768164f);
        p = fmaf(p, w, 0.246640727f);
        p = fmaf(p, w, 1.50140941f);
    } else {
        w = sqrtf(w) - 3.0f;
        p = -0.000200214257f;
        p = fmaf(p, w, 0.000100950558f);
        p = fmaf(p, w, 0.00134934322f);
        p = fmaf(p, w, -0.00367342844f);
        p = fmaf(p, w, 0.00573950773f);
        p = fmaf(p, w, -0.0076224613f);
        p = fmaf(p, w, 0.00943887047f);
        p = fmaf(p, w, 1.00167406f);
        p = fmaf(p, w, 2.83297682f);
    }
    return p * y;
}

__global__ __launch_bounds__(512) void ep_one(const float* __restrict__ x,
                                              float* __restrict__ out) {
    __shared__ double sred[NW][2];
    __shared__ double stats[2];
    __shared__ float mom[NW][NM];
    __shared__ double SnL[NM], invfL[NM], cL[NM];
    __shared__ double t2L[NPTS], t3L[NPTS];
    __shared__ float gL[NPTS];

    const int b = blockIdx.x, tid = threadIdx.x;
    const int lane = tid & 63, wv = tid >> 6;
    const float4* xr4 = (const float4*)(x + b * N_ELEM);
    const float4 va = xr4[tid];
    const float4 vb = xr4[tid + 512];

    // reference points g_k (f32, bit-matches XLA; proven absmax 0)
    if (tid < NPTS) {
        float q = 0.01f + 0.06125f * (float)tid;   // linspace(0.01,0.99,17)
        gL[tid] = erfinv_f(2.0f * q - 1.0f) * 1.41421356237309515f;
    }

    // ---- row stats (f64) ----
    {
        double a0 = va.x, a1 = va.y, a2 = va.z, a3 = va.w;
        double b0 = vb.x, b1 = vb.y, b2 = vb.z, b3 = vb.w;
        double s  = ((a0 + a1) + (a2 + a3)) + ((b0 + b1) + (b2 + b3));
        double s2 = ((a0*a0 + a1*a1) + (a2*a2 + a3*a3))
                  + ((b0*b0 + b1*b1) + (b2*b2 + b3*b3));
#pragma unroll
        for (int off = 32; off > 0; off >>= 1) {
            s  += __shfl_down(s, off, 64);
            s2 += __shfl_down(s2, off, 64);
        }
        if (lane == 0) { sred[wv][0] = s; sred[wv][1] = s2; }
    }
    __syncthreads();
    if (tid == 0) {
        double Sa = 0.0, Sb = 0.0;
#pragma unroll
        for (int w = 0; w < NW; ++w) { Sa += sred[w][0]; Sb += sred[w][1]; }
        double mean = Sa / (double)N_ELEM;
        double var  = (Sb - (double)N_ELEM * mean * mean) / (double)(N_ELEM - 1);
        stats[0] = mean;
        stats[1] = 1.0 / (sqrt(var) + 1e-6);   // torch std(ddof=1) + EPS
    }
    __syncthreads();
    const double mean = stats[0], istd = stats[1];

    // ---- normalize + Gaussian weights (f32), 8 elems/thread ----
    float xv[8], pv[8];
    {
        const float* fa = (const float*)&va;
        const float* fb = (const float*)&vb;
#pragma unroll
        for (int e = 0; e < 4; ++e) {
            xv[e]     = (float)(((double)fa[e] - mean) * istd);
            xv[e + 4] = (float)(((double)fb[e] - mean) * istd);
        }
#pragma unroll
        for (int e = 0; e < 8; ++e) pv[e] = EXP2(-HL2E * xv[e] * xv[e]);
    }

    // ---- 48 moment chains (8 independent chains for ILP) ----
    float S[NM];
#pragma unroll
    for (int n = 0; n < NM; ++n) {
        S[n] = ((pv[0] + pv[1]) + (pv[2] + pv[3]))
             + ((pv[4] + pv[5]) + (pv[6] + pv[7]));
#pragma unroll
        for (int e = 0; e < 8; ++e) pv[e] *= xv[e];
    }
#pragma unroll
    for (int n = 0; n < NM; ++n) S[n] = wave_sum63(S[n]);
    if (lane == 63) {
        float4* dst = (float4*)mom[wv];
#pragma unroll
        for (int q = 0; q < NM / 4; ++q)
            dst[q] = make_float4(S[4*q], S[4*q+1], S[4*q+2], S[4*q+3]);
    }
    __syncthreads();

    // ---- combine waves + factorials (threads 0..47) ----
    if (tid < NM) {
        double acc = 0.0;
#pragma unroll
        for (int w = 0; w < NW; ++w) acc += (double)mom[w][tid];
        double f = 1.0;
        for (int i = 2; i <= tid; ++i) f *= (double)i;   // n!
        SnL[tid] = acc;
        invfL[tid] = 1.0 / f;
        cL[tid] = acc * acc / f;
    }
    __syncthreads();

    // ---- term2 / term3 (threads 0..16) — hardware f32 exp2 only ----
    if (tid < NPTS) {
        float g = gL[tid];
        double gd = (double)g;
        double pw = 1.0, acc = 0.0;
#pragma unroll
        for (int n = 0; n < NM; ++n) { acc += SnL[n] * invfL[n] * pw; pw *= gd; }
        t2L[tid] = (double)EXP2(-HL2E * g * g) * acc;
        float a3 = 0.f;
#pragma unroll
        for (int l = 0; l < NPTS; ++l) {
            float d = g - gL[l];
            a3 += EXP2(-HL2E * d * d);
        }
        t3L[tid] = (double)a3;
    }
    __syncthreads();
    if (tid == 0) {
        double t1 = 0.0;
        for (int n = 0; n < NM; ++n) t1 += cL[n];
        t1 /= (double)N_ELEM * (double)N_ELEM;
        double s2 = 0.0, s3 = 0.0;
        for (int k = 0; k < NPTS; ++k) { s2 += t2L[k]; s3 += t3L[k]; }
        out[b] = (float)(t1 - 2.0 * s2 / ((double)N_ELEM * (double)NPTS)
                            + s3 / (double)(NPTS * NPTS));
    }
}

extern "C" void kernel_launch(void* const* d_in, const int* in_sizes, int n_in,
                              void* d_out, int out_size, void* d_ws, size_t ws_size,
                              hipStream_t stream) {
    const float* x = (const float*)d_in[0];
    float* out = (float*)d_out;
    hipLaunchKernelGGL(ep_one, dim3(BATCH), dim3(512), 0, stream, x, out);
}